// Round 1
// baseline (765.591 us; speedup 1.0000x reference)
//
#include <hip/hip_runtime.h>

#define N_NODES 100000
#define N_EDGES 1250000
#define D 64

// ---------------- zero workspace (agg + cnt) ----------------
__global__ void zero_kernel(float4* __restrict__ p, int n4) {
    int i = blockIdx.x * blockDim.x + threadIdx.x;
    if (i < n4) p[i] = make_float4(0.f, 0.f, 0.f, 0.f);
}

// ---------------- scatter: wave per edge, lane = feature ----------------
__global__ __launch_bounds__(256)
void scatter_kernel(const float* __restrict__ feat,
                    const int* __restrict__ src,
                    const int* __restrict__ dst,
                    float* __restrict__ agg,
                    float* __restrict__ cnt /* nullptr for layer 2 */) {
    int wave = (blockIdx.x * 256 + threadIdx.x) >> 6;
    int lane = threadIdx.x & 63;
    if (wave >= N_EDGES) return;
    int s = src[wave];
    int d = dst[wave];
    float v = feat[s * D + lane];
    atomicAdd(&agg[d * D + lane], v);
    if (cnt != nullptr && lane == 0) atomicAdd(&cnt[d], 1.0f);
}

// ---------------- dense: out = mean@Wl + b + xin@Wr (opt relu) ----------------
// 64-node tile per block, 256 threads, 4x4 register tile per thread.
// zero_agg: writes zeros back to agg rows after reading (prepares scatter2).
__global__ __launch_bounds__(256, 2)
void dense_kernel(const float* __restrict__ xin,
                  float* __restrict__ agg,
                  const float* __restrict__ cnt,
                  const float* __restrict__ Wl,
                  const float* __restrict__ bl,
                  const float* __restrict__ Wr,
                  float* __restrict__ out,
                  int relu, int zero_agg) {
    __shared__ float sM[64][68];   // mean rows   (pad 68: A-reads 2-way max)
    __shared__ float sX[64][68];   // xin rows
    __shared__ float sWl[64][64];  // W row-major [k][j]
    __shared__ float sWr[64][64];

    const int tid = threadIdx.x;
    const int row0 = blockIdx.x * 64;

    // stage W (4096 floats each = 1024 float4)
    for (int i = tid; i < 1024; i += 256) {
        ((float4*)&sWl[0][0])[i] = ((const float4*)Wl)[i];
        ((float4*)&sWr[0][0])[i] = ((const float4*)Wr)[i];
    }

    // stage A tiles: 4 passes of 16 rows, float4 per thread
    const int c4 = (tid & 15) * 4;
    for (int p = 0; p < 4; ++p) {
        int r = p * 16 + (tid >> 4);
        int n = row0 + r;
        float4 xv = make_float4(0.f, 0.f, 0.f, 0.f);
        float4 av = xv;
        float inv = 0.f;
        if (n < N_NODES) {
            xv = *(const float4*)&xin[n * D + c4];
            av = *(const float4*)&agg[n * D + c4];
            float c = cnt[n];
            inv = 1.0f / fmaxf(c, 1.0f);
            if (zero_agg)
                *(float4*)&agg[n * D + c4] = make_float4(0.f, 0.f, 0.f, 0.f);
        }
        *(float4*)&sX[r][c4] = xv;
        *(float4*)&sM[r][c4] = make_float4(av.x * inv, av.y * inv, av.z * inv, av.w * inv);
    }
    __syncthreads();

    const int tx = tid & 15, ty = tid >> 4;
    const int j0 = tx * 4;
    const int i0 = ty * 4;

    float acc[4][4];
    float4 b4 = *(const float4*)&bl[j0];
#pragma unroll
    for (int i = 0; i < 4; ++i) {
        acc[i][0] = b4.x; acc[i][1] = b4.y; acc[i][2] = b4.z; acc[i][3] = b4.w;
    }

    for (int k = 0; k < 64; k += 4) {
        float4 wl[4], wr[4];
#pragma unroll
        for (int kk = 0; kk < 4; ++kk) {
            wl[kk] = *(const float4*)&sWl[k + kk][j0];
            wr[kk] = *(const float4*)&sWr[k + kk][j0];
        }
#pragma unroll
        for (int i = 0; i < 4; ++i) {
            float4 m  = *(const float4*)&sM[i0 + i][k];
            float4 xv = *(const float4*)&sX[i0 + i][k];
            float mk[4] = {m.x, m.y, m.z, m.w};
            float xk[4] = {xv.x, xv.y, xv.z, xv.w};
#pragma unroll
            for (int kk = 0; kk < 4; ++kk) {
                acc[i][0] += mk[kk] * wl[kk].x + xk[kk] * wr[kk].x;
                acc[i][1] += mk[kk] * wl[kk].y + xk[kk] * wr[kk].y;
                acc[i][2] += mk[kk] * wl[kk].z + xk[kk] * wr[kk].z;
                acc[i][3] += mk[kk] * wl[kk].w + xk[kk] * wr[kk].w;
            }
        }
    }

#pragma unroll
    for (int i = 0; i < 4; ++i) {
        int n = row0 + i0 + i;
        if (n < N_NODES) {
            float4 o;
            o.x = relu ? fmaxf(acc[i][0], 0.f) : acc[i][0];
            o.y = relu ? fmaxf(acc[i][1], 0.f) : acc[i][1];
            o.z = relu ? fmaxf(acc[i][2], 0.f) : acc[i][2];
            o.w = relu ? fmaxf(acc[i][3], 0.f) : acc[i][3];
            *(float4*)&out[n * D + j0] = o;
        }
    }
}

extern "C" void kernel_launch(void* const* d_in, const int* in_sizes, int n_in,
                              void* d_out, int out_size, void* d_ws, size_t ws_size,
                              hipStream_t stream) {
    const float* x   = (const float*)d_in[0];
    const int*   ei  = (const int*)d_in[1];
    const float* Wl1 = (const float*)d_in[2];
    const float* b1  = (const float*)d_in[3];
    const float* Wr1 = (const float*)d_in[4];
    const float* Wl2 = (const float*)d_in[5];
    const float* b2  = (const float*)d_in[6];
    const float* Wr2 = (const float*)d_in[7];

    const int* src = ei;             // edge_index[0]
    const int* dst = ei + N_EDGES;   // edge_index[1]

    float* agg = (float*)d_ws;                 // [N, D]
    float* cnt = agg + (size_t)N_NODES * D;    // [N]
    float* out = (float*)d_out;                // doubles as h buffer

    // zero agg + cnt (contiguous): (N*D + N) floats = 6,500,000 -> 1,625,000 float4
    const int n4 = (N_NODES * D + N_NODES) / 4;
    zero_kernel<<<(n4 + 255) / 256, 256, 0, stream>>>((float4*)agg, n4);

    const int scatter_blocks = (N_EDGES + 3) / 4;   // 4 edges (waves) per block
    const int dense_blocks = (N_NODES + 63) / 64;

    // Layer 1
    scatter_kernel<<<scatter_blocks, 256, 0, stream>>>(x, src, dst, agg, cnt);
    dense_kernel<<<dense_blocks, 256, 0, stream>>>(x, agg, cnt, Wl1, b1, Wr1, out,
                                                   /*relu=*/1, /*zero_agg=*/1);
    // Layer 2 (h lives in d_out; dense2 is safely in-place per 64-row tile)
    scatter_kernel<<<scatter_blocks, 256, 0, stream>>>(out, src, dst, agg, nullptr);
    dense_kernel<<<dense_blocks, 256, 0, stream>>>(out, agg, cnt, Wl2, b2, Wr2, out,
                                                   /*relu=*/0, /*zero_agg=*/0);
}